// Round 2
// baseline (14738.171 us; speedup 1.0000x reference)
//
#include <hip/hip_runtime.h>
#include <stdint.h>
#include <stddef.h>

typedef unsigned short u16;
typedef unsigned int u32;

typedef __attribute__((ext_vector_type(8))) short bf16x8;   // 8 bf16 (MFMA A/B frag)
typedef __attribute__((ext_vector_type(4))) float f32x4;    // MFMA C/D frag

#define DEV __device__ __forceinline__

DEV u16 f2bf(float f) {
  union { float f; u32 u; } v; v.f = f;
  u32 r = v.u + 0x7FFFu + ((v.u >> 16) & 1u);   // RNE
  return (u16)(r >> 16);
}
DEV float bf2f(u16 h) {
  union { u32 u; float f; } v; v.u = ((u32)h) << 16;
  return v.f;
}
DEV float frcp(float x) { return __builtin_amdgcn_rcpf(x); }
DEV float sigm(float x) { return frcp(1.0f + __expf(-x)); }
DEV float tanh_(float x) { return 2.0f * frcp(1.0f + __expf(-2.0f * x)) - 1.0f; }

DEV void pack8(const float* __restrict__ src, u16* dst) {
  float4 x = *(const float4*)src;
  float4 y = *(const float4*)(src + 4);
  union { u16 us[8]; uint4 v; } t;
  t.us[0] = f2bf(x.x); t.us[1] = f2bf(x.y); t.us[2] = f2bf(x.z); t.us[3] = f2bf(x.w);
  t.us[4] = f2bf(y.x); t.us[5] = f2bf(y.y); t.us[6] = f2bf(y.z); t.us[7] = f2bf(y.w);
  *(uint4*)dst = t.v;
}

// ---------------------------------------------------------------------------
// Grid barrier: monotone arrival counter, release/acquire fences.
// Co-residency by capacity arithmetic (NOT cooperative launch, which fails
// under graph capture): grid=256 blocks = #CUs; LDS 43KB -> 3 blocks/CU
// capacity; VGPR<=256 -> >=1 block/CU; so all 256 blocks are dispatched
// immediately and resident -> barrier cannot deadlock.
// ---------------------------------------------------------------------------
DEV void gsync(int* bar, int target) {
  __threadfence();                         // release prior writes to device scope
  __syncthreads();
  if (threadIdx.x == 0) {
    __hip_atomic_fetch_add(bar, 1, __ATOMIC_ACQ_REL, __HIP_MEMORY_SCOPE_AGENT);
    while (__hip_atomic_load(bar, __ATOMIC_ACQUIRE, __HIP_MEMORY_SCOPE_AGENT) < target)
      __builtin_amdgcn_s_sleep(4);
    __threadfence();                       // acquire: invalidate caches before reads
  }
  __syncthreads();
}

__global__ void zero_bar_k(int* bar) { *bar = 0; }

// ---------------------------------------------------------------------------
// 128x128-tile bf16 MFMA GEMM, C = A[M,K] * B[N,K]^T + bias.  (unchanged)
// ---------------------------------------------------------------------------
__global__ __launch_bounds__(256) void gemm128_bt(
    const u16* __restrict__ A, int lda,
    const void* __restrict__ Bv, int ldb, int b_fp32,
    const float* __restrict__ bias,
    void* __restrict__ Cv, int ldc, int c_bf16,
    int N, int K, int swz)
{
  int m_tile, n_tile;
  if (swz) {
    int lin = blockIdx.y * gridDim.x + blockIdx.x;
    int idx = lin & 127;
    n_tile = (lin >> 7) * 8 + (idx & 7);
    m_tile = idx >> 3;
    if (n_tile >= ((N + 127) >> 7)) return;
  } else { m_tile = blockIdx.x; n_tile = blockIdx.y; }
  const int mBase = m_tile * 128;
  const int nBase = n_tile * 128;
  __shared__ u16 As[128 * 40];
  __shared__ u16 Bs[128 * 40];
  const int tid = threadIdx.x;
  const int lane = tid & 63;
  const int w = tid >> 6;
  const int wm = w >> 1, wn = w & 1;
  const int fr = (lane & 15);
  const int fq = (lane >> 4);

  f32x4 acc[4][4] = {};
  const int nk = K >> 5;
  for (int kt = 0; kt < nk; ++kt) {
    const int k0 = kt << 5;
    {
      int row0 = tid >> 2, k8 = (tid & 3) << 3;
      *(uint4*)&As[row0 * 40 + k8] =
          *(const uint4*)(A + (size_t)(mBase + row0) * lda + k0 + k8);
      int row1 = row0 + 64;
      *(uint4*)&As[row1 * 40 + k8] =
          *(const uint4*)(A + (size_t)(mBase + row1) * lda + k0 + k8);
    }
    {
      int row0 = tid >> 2, k8 = (tid & 3) << 3;
      for (int q = 0; q < 2; ++q) {
        int row = row0 + q * 64;
        int brow = nBase + row; if (brow > N - 1) brow = N - 1;
        if (b_fp32) {
          pack8((const float*)Bv + (size_t)brow * ldb + k0 + k8, &Bs[row * 40 + k8]);
        } else {
          *(uint4*)&Bs[row * 40 + k8] =
              *(const uint4*)((const u16*)Bv + (size_t)brow * ldb + k0 + k8);
        }
      }
    }
    __syncthreads();
    bf16x8 af[4], bfr[4];
#pragma unroll
    for (int i = 0; i < 4; ++i) {
      af[i]  = *(const bf16x8*)&As[(wm * 64 + i * 16 + fr) * 40 + fq * 8];
      bfr[i] = *(const bf16x8*)&Bs[(wn * 64 + i * 16 + fr) * 40 + fq * 8];
    }
#pragma unroll
    for (int mi = 0; mi < 4; ++mi)
#pragma unroll
      for (int ni = 0; ni < 4; ++ni)
        acc[mi][ni] = __builtin_amdgcn_mfma_f32_16x16x32_bf16(af[mi], bfr[ni], acc[mi][ni], 0, 0, 0);
    __syncthreads();
  }
#pragma unroll
  for (int mi = 0; mi < 4; ++mi) {
    int row = mBase + wm * 64 + mi * 16 + fq * 4;
#pragma unroll
    for (int ni = 0; ni < 4; ++ni) {
      int col = nBase + wn * 64 + ni * 16 + fr;
      if (col < N) {
        float bv = bias ? bias[col] : 0.0f;
#pragma unroll
        for (int r = 0; r < 4; ++r) {
          float v = acc[mi][ni][r] + bv;
          if (c_bf16) ((u16*)Cv)[(size_t)(row + r) * ldc + col] = f2bf(v);
          else        ((float*)Cv)[(size_t)(row + r) * ldc + col] = v;
        }
      }
    }
  }
}

// ---------------------------------------------------------------------------
// Setup-only M=64 GEMM (h0/c0).  (unchanged)
// ---------------------------------------------------------------------------
__global__ __launch_bounds__(256) void gemm64_bt(
    const u16* __restrict__ A, int lda,
    const float* __restrict__ B, int ldb,
    const float* __restrict__ bias,
    float* __restrict__ C, int ldc, int K)
{
  const int nBase = blockIdx.x * 64;
  __shared__ u16 As[64 * 40];
  __shared__ u16 Bs[64 * 40];
  const int tid = threadIdx.x;
  const int lane = tid & 63;
  const int w = tid >> 6;
  const int wm = w >> 1, wn = w & 1;
  const int fr = (lane & 15), fq = (lane >> 4);

  f32x4 acc[2][2] = {};
  const int nk = K >> 5;
  for (int kt = 0; kt < nk; ++kt) {
    const int k0 = kt << 5;
    int row = tid >> 2, k8 = (tid & 3) << 3;
    *(uint4*)&As[row * 40 + k8] = *(const uint4*)(A + (size_t)row * lda + k0 + k8);
    pack8(B + (size_t)(nBase + row) * ldb + k0 + k8, &Bs[row * 40 + k8]);
    __syncthreads();
    bf16x8 af[2], bfr[2];
#pragma unroll
    for (int i = 0; i < 2; ++i) {
      af[i]  = *(const bf16x8*)&As[(wm * 32 + i * 16 + fr) * 40 + fq * 8];
      bfr[i] = *(const bf16x8*)&Bs[(wn * 32 + i * 16 + fr) * 40 + fq * 8];
    }
#pragma unroll
    for (int mi = 0; mi < 2; ++mi)
#pragma unroll
      for (int ni = 0; ni < 2; ++ni)
        acc[mi][ni] = __builtin_amdgcn_mfma_f32_16x16x32_bf16(af[mi], bfr[ni], acc[mi][ni], 0, 0, 0);
    __syncthreads();
  }
#pragma unroll
  for (int mi = 0; mi < 2; ++mi) {
    int row = wm * 32 + mi * 16 + fq * 4;
#pragma unroll
    for (int ni = 0; ni < 2; ++ni) {
      int col = nBase + wn * 32 + ni * 16 + fr;
#pragma unroll
      for (int r = 0; r < 4; ++r)
        C[(size_t)(row + r) * ldc + col] = acc[mi][ni][r] + bias[col];
    }
  }
}

// ---------------------------------------------------------------------------
// Persistent kernel: the full 32-step recurrence in ONE launch.
// Grid = 256 blocks x 256 threads.  Per step:
//   Phase A: blocks 0-127  = attend (b=bid>>1, which=bid&1), incl. in-block
//            w_ah matvec (replaces step_wah kernel);
//            blocks 128-255 = Ghh tile (j,mg): h @ Whh^T (K in [1280,1792)).
//   gsync
//   Phase B: blocks 0-127  = gates over K in [0,1280) ([ctx|pctx] @ Wih'),
//            epilogue adds Ghh + Gemb, runs LSTM cell -> h,c, Hall.
//   gsync
// ---------------------------------------------------------------------------
__global__ __launch_bounds__(256) void step_loop(
    const u16* __restrict__ u_feat, const u16* __restrict__ u_art,
    const u16* __restrict__ feats_bf, const u16* __restrict__ arts_bf,
    const u16* __restrict__ Watt,
    const float* __restrict__ attWb, const float* __restrict__ paWb,
    const float* __restrict__ attAw, const float* __restrict__ attAb,
    const float* __restrict__ paAw, const float* __restrict__ paAb,
    const u16* __restrict__ Wg, const float* __restrict__ Gemb,
    float* __restrict__ Ghh,
    u16* __restrict__ Abuf, float* __restrict__ cbuf, u16* __restrict__ Hall,
    float* __restrict__ out_alpha, float* __restrict__ out_pa,
    int* __restrict__ bar)
{
  const int bid = blockIdx.x;
  const int tid = threadIdx.x;
  const int lane = tid & 63;
  const int w = tid >> 6;

  __shared__ float hs[512];          // h[b] as fp32 (attend path)
  __shared__ float wvs[512];         // w_ah slice (attend path)
  __shared__ float sc[196];
  __shared__ float red2[2];
  __shared__ float ctxred[4][768];
  __shared__ u16 As[16 * 136];       // gemm paths
  __shared__ u16 Bs[64 * 136];
  __shared__ float Gex[4][256];

  // attend-role constants
  const int which = bid & 1, b = bid >> 1;
  const int Nn = which ? 64 : 196;
  const int Dd = which ? 768 : 512;
  const u16* u  = which ? u_art + (size_t)b * 64 * 512 : u_feat + (size_t)b * 196 * 512;
  const u16* fe = which ? arts_bf + (size_t)b * 64 * 768 : feats_bf + (size_t)b * 196 * 512;
  const float* Aw = which ? paAw : attAw;
  const float Ab = which ? paAb[0] : attAb[0];
  const float* Wb = which ? paWb : attWb;
  const u16* Wrow0 = Watt + (size_t)(which * 512 + tid * 2) * 512;
  u16* ctxDst = Abuf + (size_t)b * 1792 + (which ? 512 : 0);

  // gemm-role constants
  const int gj = bid & 31, gmg = (bid >> 5) & 3;    // Phase B (bid<128)
  const int hidx = bid - 128;
  const int hj = hidx & 31, hmg = hidx >> 5;        // Phase A Ghh (bid>=128)
  const int g = w;                                  // wave = gate
  const int fr = lane & 15, fq = lane >> 4;

  float awr[8];
  if (bid < 128) {
#pragma unroll
    for (int j = 0; j < 8; ++j) awr[j] = Aw[lane * 8 + j];
  }

  int tgt = 0;
  for (int t = 0; t < 32; ++t) {
    // ================= Phase A =================
    if (bid < 128) {
      // ---- h -> LDS (fp32) ----
      if (tid < 64) {
        union { uint4 v; u16 us[8]; } hv;
        hv.v = *(const uint4*)(Abuf + (size_t)b * 1792 + 1280 + tid * 8);
#pragma unroll
        for (int j = 0; j < 8; ++j) hs[tid * 8 + j] = bf2f(hv.us[j]);
      }
      __syncthreads();
      // ---- wv = h @ Watt_half^T + Wb  (thread owns cols 2*tid, 2*tid+1) ----
      {
        float a0 = 0.0f, a1 = 0.0f;
        for (int k = 0; k < 512; k += 8) {
          union { uint4 v; u16 us[8]; } r0, r1;
          r0.v = *(const uint4*)(Wrow0 + k);
          r1.v = *(const uint4*)(Wrow0 + 512 + k);
#pragma unroll
          for (int j = 0; j < 8; ++j) {
            float hv = hs[k + j];
            a0 += bf2f(r0.us[j]) * hv;
            a1 += bf2f(r1.us[j]) * hv;
          }
        }
        wvs[tid * 2]     = a0 + Wb[tid * 2];
        wvs[tid * 2 + 1] = a1 + Wb[tid * 2 + 1];
      }
      __syncthreads();
      float wvr[8];
#pragma unroll
      for (int j = 0; j < 8; ++j) wvr[j] = wvs[lane * 8 + j];
      // ---- scores ----
      for (int n = w; n < Nn; n += 4) {
        union { uint4 v; u16 us[8]; } uv;
        uv.v = *(const uint4*)(u + (size_t)n * 512 + lane * 8);
        float p = 0.0f;
#pragma unroll
        for (int j = 0; j < 8; ++j)
          p += tanh_(bf2f(uv.us[j]) + wvr[j]) * awr[j];
#pragma unroll
        for (int off = 32; off > 0; off >>= 1) p += __shfl_down(p, off);
        if (lane == 0) sc[n] = p + Ab;
      }
      __syncthreads();
      // ---- softmax stats ----
      if (w == 0) {
        float m = -1e30f;
        for (int n = lane; n < Nn; n += 64) m = fmaxf(m, sc[n]);
#pragma unroll
        for (int off = 32; off > 0; off >>= 1) m = fmaxf(m, __shfl_xor(m, off));
        float s = 0.0f;
        for (int n = lane; n < Nn; n += 64) s += __expf(sc[n] - m);
#pragma unroll
        for (int off = 32; off > 0; off >>= 1) s += __shfl_xor(s, off);
        if (lane == 0) { red2[0] = m; red2[1] = s; }
      }
      __syncthreads();
      const float m = red2[0], inv = frcp(red2[1]);
      float* aout = which ? out_pa + (size_t)(b * 32 + t) * 64
                          : out_alpha + (size_t)(b * 32 + t) * 196;
      for (int n = tid; n < Nn; n += 256) {
        float a = __expf(sc[n] - m) * inv;
        sc[n] = a;
        aout[n] = a;
      }
      __syncthreads();
      // ---- ctx ----
      float a0[8] = {0,0,0,0,0,0,0,0}, a1[8] = {0,0,0,0,0,0,0,0};
      const bool two = (Dd == 768) && (lane < 32);
      for (int n = w; n < Nn; n += 4) {
        const float a = sc[n];
        union { uint4 v; u16 us[8]; } v0;
        v0.v = *(const uint4*)(fe + (size_t)n * Dd + lane * 8);
#pragma unroll
        for (int j = 0; j < 8; ++j) a0[j] += a * bf2f(v0.us[j]);
        if (two) {
          union { uint4 v; u16 us[8]; } v1;
          v1.v = *(const uint4*)(fe + (size_t)n * Dd + 512 + lane * 8);
#pragma unroll
          for (int j = 0; j < 8; ++j) a1[j] += a * bf2f(v1.us[j]);
        }
      }
      {
        float4* dst = (float4*)&ctxred[w][lane * 8];
        dst[0] = make_float4(a0[0], a0[1], a0[2], a0[3]);
        dst[1] = make_float4(a0[4], a0[5], a0[6], a0[7]);
        if (two) {
          float4* d2 = (float4*)&ctxred[w][512 + lane * 8];
          d2[0] = make_float4(a1[0], a1[1], a1[2], a1[3]);
          d2[1] = make_float4(a1[4], a1[5], a1[6], a1[7]);
        }
      }
      __syncthreads();
      for (int d = tid; d < Dd; d += 256)
        ctxDst[d] = f2bf(ctxred[0][d] + ctxred[1][d] + ctxred[2][d] + ctxred[3][d]);
    } else {
      // ---- Ghh tile: h @ Whh^T  (Wg cols [1280,1792)) ----
      f32x4 acc = {};
      for (int kt = 10; kt < 14; ++kt) {
        const int k0 = kt * 128;
        {
          int r = tid >> 4, kc = (tid & 15) << 3;
          *(uint4*)&As[r * 136 + kc] =
              *(const uint4*)(Abuf + (size_t)(hmg * 16 + r) * 1792 + k0 + kc);
        }
#pragma unroll
        for (int q = 0; q < 4; ++q) {
          int idx = tid + q * 256;
          int r6 = idx >> 4, kc = (idx & 15) << 3;
          int gg = r6 >> 4, rr = r6 & 15;
          *(uint4*)&Bs[r6 * 136 + kc] =
              *(const uint4*)(Wg + (size_t)(gg * 512 + hj * 16 + rr) * 1792 + k0 + kc);
        }
        __syncthreads();
#pragma unroll
        for (int ks = 0; ks < 4; ++ks) {
          bf16x8 af = *(const bf16x8*)&As[fr * 136 + ks * 32 + fq * 8];
          bf16x8 bf = *(const bf16x8*)&Bs[(g * 16 + fr) * 136 + ks * 32 + fq * 8];
          acc = __builtin_amdgcn_mfma_f32_16x16x32_bf16(af, bf, acc, 0, 0, 0);
        }
        __syncthreads();
      }
#pragma unroll
      for (int r = 0; r < 4; ++r)
        Ghh[(size_t)(hmg * 16 + fq * 4 + r) * 2048 + g * 512 + hj * 16 + fr] = acc[r];
    }
    tgt += 256; gsync(bar, tgt);
    // ================= Phase B =================
    if (bid < 128) {
      f32x4 acc = {};
      for (int kt = 0; kt < 10; ++kt) {
        const int k0 = kt * 128;
        {
          int r = tid >> 4, kc = (tid & 15) << 3;
          *(uint4*)&As[r * 136 + kc] =
              *(const uint4*)(Abuf + (size_t)(gmg * 16 + r) * 1792 + k0 + kc);
        }
#pragma unroll
        for (int q = 0; q < 4; ++q) {
          int idx = tid + q * 256;
          int r6 = idx >> 4, kc = (idx & 15) << 3;
          int gg = r6 >> 4, rr = r6 & 15;
          *(uint4*)&Bs[r6 * 136 + kc] =
              *(const uint4*)(Wg + (size_t)(gg * 512 + gj * 16 + rr) * 1792 + k0 + kc);
        }
        __syncthreads();
#pragma unroll
        for (int ks = 0; ks < 4; ++ks) {
          bf16x8 af = *(const bf16x8*)&As[fr * 136 + ks * 32 + fq * 8];
          bf16x8 bf = *(const bf16x8*)&Bs[(g * 16 + fr) * 136 + ks * 32 + fq * 8];
          acc = __builtin_amdgcn_mfma_f32_16x16x32_bf16(af, bf, acc, 0, 0, 0);
        }
        __syncthreads();
      }
#pragma unroll
      for (int r = 0; r < 4; ++r)
        Gex[g][(fq * 4 + r) * 16 + fr] = acc[r];
      __syncthreads();
      {
        const int bl = tid >> 4, dl = tid & 15;
        const int bb = gmg * 16 + bl;
        const int d = gj * 16 + dl;
        const float* ge = Gemb + (size_t)(bb * 32 + t) * 2048;
        const float* gh = Ghh + (size_t)bb * 2048;
        float iv = Gex[0][tid] + ge[d]        + gh[d];
        float fv = Gex[1][tid] + ge[512 + d]  + gh[512 + d];
        float gv = Gex[2][tid] + ge[1024 + d] + gh[1024 + d];
        float ov = Gex[3][tid] + ge[1536 + d] + gh[1536 + d];
        float c_old = cbuf[bb * 512 + d];
        float cn = sigm(fv) * c_old + sigm(iv) * tanh_(gv);
        float hn = sigm(ov) * tanh_(cn);
        cbuf[bb * 512 + d] = cn;
        u16 hb = f2bf(hn);
        Abuf[(size_t)bb * 1792 + 1280 + d] = hb;
        Hall[(size_t)(bb * 32 + t) * 512 + d] = hb;
      }
    }
    tgt += 256; gsync(bar, tgt);
  }
}

// --------------------------- small setup kernels ---------------------------

__global__ void convert_bf16_k(const float* __restrict__ src, u16* __restrict__ dst) {
  size_t i4 = ((size_t)blockIdx.x * 256 + threadIdx.x) * 4;
  float4 v = *(const float4*)(src + i4);
  union { u16 us[4]; uint2 u; } t;
  t.us[0] = f2bf(v.x); t.us[1] = f2bf(v.y); t.us[2] = f2bf(v.z); t.us[3] = f2bf(v.w);
  *(uint2*)(dst + i4) = t.u;
}

// W_gates[2048,1792] bf16 = [Wih cols 512:1792 | Whh cols 0:512]
__global__ void wgates_k(const float* __restrict__ Wih, const float* __restrict__ Whh,
                         u16* __restrict__ dst) {
  int c = blockIdx.x * 256 + threadIdx.x;     // 458752 chunk-8s
  int r = c / 224;
  int k8 = (c - r * 224) * 8;
  const float* src = (k8 < 1280) ? (Wih + (size_t)r * 1792 + 512 + k8)
                                 : (Whh + (size_t)r * 512 + (k8 - 1280));
  pack8(src, dst + (size_t)r * 1792 + k8);
}

__global__ void biassum_k(const float* __restrict__ a, const float* __restrict__ b,
                          float* __restrict__ dst) {
  int i = blockIdx.x * 256 + threadIdx.x;
  dst[i] = a[i] + b[i];
}

__global__ void gather_emb_k(const int* __restrict__ captions, const float* __restrict__ emb,
                             u16* __restrict__ Emb_all) {
  int c = blockIdx.x * 256 + threadIdx.x;
  int r = c >> 7;
  int c4 = (c & 127) << 2;
  int v = captions[r];
  float4 x = *(const float4*)(emb + (size_t)v * 512 + c4);
  union { u16 us[4]; uint2 u; } t;
  t.us[0] = f2bf(x.x); t.us[1] = f2bf(x.y); t.us[2] = f2bf(x.z); t.us[3] = f2bf(x.w);
  *(uint2*)(Emb_all + (size_t)r * 512 + c4) = t.u;
}

__global__ void meanpool_k(const float* __restrict__ features, const float* __restrict__ articles,
                           u16* __restrict__ inp0_bf) {
  int b = blockIdx.x, tid = threadIdx.x;
  for (int d = tid; d < 1280; d += 256) {
    float s = 0.0f;
    if (d < 512) {
      for (int n = 0; n < 196; ++n) s += features[((size_t)b * 196 + n) * 512 + d];
      s *= (1.0f / 196.0f);
    } else {
      int dd = d - 512;
      for (int n = 0; n < 64; ++n) s += articles[((size_t)b * 64 + n) * 768 + dd];
      s *= (1.0f / 64.0f);
    }
    inp0_bf[b * 1280 + d] = f2bf(s);
  }
}

__global__ void h0prep_k(const float* __restrict__ hbuf, u16* __restrict__ Abuf) {
  int i = blockIdx.x * 256 + threadIdx.x;     // 32768
  Abuf[(size_t)(i >> 9) * 1792 + 1280 + (i & 511)] = f2bf(hbuf[i]);
}

// ---------------------------------------------------------------------------

extern "C" void kernel_launch(void* const* d_in, const int* in_sizes, int n_in,
                              void* d_out, int out_size, void* d_ws, size_t ws_size,
                              hipStream_t stream) {
  const float* features = (const float*)d_in[0];
  const float* articles = (const float*)d_in[1];
  const int*   captions = (const int*)d_in[2];
  const float* emb      = (const float*)d_in[3];
  const float* att_W_w  = (const float*)d_in[4];
  const float* att_W_b  = (const float*)d_in[5];
  const float* att_U_w  = (const float*)d_in[6];
  const float* att_U_b  = (const float*)d_in[7];
  const float* att_A_w  = (const float*)d_in[8];
  const float* att_A_b  = (const float*)d_in[9];
  const float* pa_W_w   = (const float*)d_in[10];
  const float* pa_W_b   = (const float*)d_in[11];
  const float* pa_U_w   = (const float*)d_in[12];
  const float* pa_U_b   = (const float*)d_in[13];
  const float* pa_A_w   = (const float*)d_in[14];
  const float* pa_A_b   = (const float*)d_in[15];
  const float* init_h_w = (const float*)d_in[16];
  const float* init_h_b = (const float*)d_in[17];
  const float* init_c_w = (const float*)d_in[18];
  const float* init_c_b = (const float*)d_in[19];
  const float* lstm_w_ih = (const float*)d_in[20];
  const float* lstm_w_hh = (const float*)d_in[21];
  const float* lstm_b_ih = (const float*)d_in[22];
  const float* lstm_b_hh = (const float*)d_in[23];
  const float* fcn_w    = (const float*)d_in[24];
  const float* fcn_b    = (const float*)d_in[25];

  float* out = (float*)d_out;
  float* out_preds = out;                       // [64,32,30000]
  float* out_alpha = out + 61440000ull;         // [64,32,196]
  float* out_pa    = out + 61841408ull;         // [64,32,64]

  uintptr_t p = (uintptr_t)d_ws;
  auto take = [&](size_t bytes) -> uintptr_t {
    uintptr_t r = p; p += (bytes + 255) & ~(size_t)255; return r;
  };
  u16* features_bf = (u16*)take(6422528ull * 2);   // [64*196,512]; fcn_bf alias after loop
  u16* articles_bf = (u16*)take(3145728ull * 2);   // [64*64,768]
  u16* u_feat      = (u16*)take(6422528ull * 2);   // [64*196,512]
  u16* u_art       = (u16*)take(2097152ull * 2);   // [64*64,512]
  u16* Emb_all     = (u16*)take(2048ull * 512 * 2);
  u16* inp0_bf     = (u16*)take(64ull * 1280 * 2);
  float* hbuf      = (float*)take(64ull * 512 * 4);
  float* cbuf      = (float*)take(64ull * 512 * 4);
  u16* Abuf        = (u16*)take(64ull * 1792 * 2); // [ctx|pctx|h] per b
  float* Ghh       = (float*)take(64ull * 2048 * 4); // h @ Whh^T per step
  u16* Hall        = (u16*)take(2048ull * 512 * 2);
  u16* Watt        = (u16*)take(1024ull * 512 * 2);
  u16* Wg          = (u16*)take(2048ull * 1792 * 2);
  float* Gemb      = (float*)take(2048ull * 2048 * 4);
  float* bsum      = (float*)take(2048ull * 4);
  int* bar         = (int*)take(256);
  u16* fcn_bf      = features_bf;                  // aliased (dead after loop)
  (void)ws_size; (void)in_sizes; (void)n_in; (void)out_size;

  // ---- one-time setup ----
  convert_bf16_k<<<6272, 256, 0, stream>>>(features, features_bf);
  convert_bf16_k<<<3072, 256, 0, stream>>>(articles, articles_bf);
  convert_bf16_k<<<256, 256, 0, stream>>>(att_W_w, Watt);
  convert_bf16_k<<<256, 256, 0, stream>>>(pa_W_w, Watt + 262144);
  wgates_k<<<1792, 256, 0, stream>>>(lstm_w_ih, lstm_w_hh, Wg);
  biassum_k<<<8, 256, 0, stream>>>(lstm_b_ih, lstm_b_hh, bsum);
  gather_emb_k<<<1024, 256, 0, stream>>>(captions, emb, Emb_all);
  meanpool_k<<<64, 256, 0, stream>>>(features, articles, inp0_bf);
  gemm128_bt<<<dim3(98, 4), 256, 0, stream>>>(features_bf, 512, att_U_w, 512, 1,
                                              att_U_b, u_feat, 512, 1, 512, 512, 0);
  gemm128_bt<<<dim3(32, 4), 256, 0, stream>>>(articles_bf, 768, pa_U_w, 768, 1,
                                              pa_U_b, u_art, 512, 1, 512, 768, 0);
  // Gemb[2048,2048] = Emb_all @ Wih[:, :512]^T + (bih + bhh)
  gemm128_bt<<<dim3(16, 16), 256, 0, stream>>>(Emb_all, 512, lstm_w_ih, 1792, 1,
                                               bsum, Gemb, 2048, 0, 2048, 512, 0);
  gemm64_bt<<<8, 256, 0, stream>>>(inp0_bf, 1280, init_h_w, 1280, init_h_b, hbuf, 512, 1280);
  gemm64_bt<<<8, 256, 0, stream>>>(inp0_bf, 1280, init_c_w, 1280, init_c_b, cbuf, 512, 1280);
  h0prep_k<<<128, 256, 0, stream>>>(hbuf, Abuf);

  // ---- recurrence: single persistent kernel (plain launch; co-residency by
  // capacity: 256 blocks = #CUs, LDS 43KB -> 3 blocks/CU capacity) ----
  zero_bar_k<<<1, 1, 0, stream>>>(bar);
  step_loop<<<dim3(256), dim3(256), 0, stream>>>(
      u_feat, u_art, features_bf, articles_bf, Watt,
      att_W_b, pa_W_b, att_A_w, att_A_b, pa_A_w, pa_A_b,
      Wg, Gemb, Ghh, Abuf, cbuf, Hall, out_alpha, out_pa, bar);

  // ---- preds = Hall @ fcn_w^T + fcn_b (fcn_bf aliases dead staging region) ----
  convert_bf16_k<<<15000, 256, 0, stream>>>(fcn_w, fcn_bf);
  gemm128_bt<<<dim3(16, 240), 256, 0, stream>>>(Hall, 512, fcn_bf, 512, 0,
                                                fcn_b, out_preds, 30000, 0,
                                                30000, 512, 1);
}

// Round 3
// 3800.746 us; speedup vs baseline: 3.8777x; 3.8777x over previous
//
#include <hip/hip_runtime.h>
#include <stdint.h>
#include <stddef.h>

typedef unsigned short u16;
typedef unsigned int u32;

typedef __attribute__((ext_vector_type(8))) short bf16x8;   // 8 bf16 (MFMA A/B frag)
typedef __attribute__((ext_vector_type(4))) float f32x4;    // MFMA C/D frag

#define DEV __device__ __forceinline__

DEV u16 f2bf(float f) {
  union { float f; u32 u; } v; v.f = f;
  u32 r = v.u + 0x7FFFu + ((v.u >> 16) & 1u);   // RNE
  return (u16)(r >> 16);
}
DEV float bf2f(u16 h) {
  union { u32 u; float f; } v; v.u = ((u32)h) << 16;
  return v.f;
}
DEV float frcp(float x) { return __builtin_amdgcn_rcpf(x); }
DEV float sigm(float x) { return frcp(1.0f + __expf(-x)); }
DEV float tanh_(float x) { return 2.0f * frcp(1.0f + __expf(-2.0f * x)) - 1.0f; }

DEV void pack8(const float* __restrict__ src, u16* dst) {
  float4 x = *(const float4*)src;
  float4 y = *(const float4*)(src + 4);
  union { u16 us[8]; uint4 v; } t;
  t.us[0] = f2bf(x.x); t.us[1] = f2bf(x.y); t.us[2] = f2bf(x.z); t.us[3] = f2bf(x.w);
  t.us[4] = f2bf(y.x); t.us[5] = f2bf(y.y); t.us[6] = f2bf(y.z); t.us[7] = f2bf(y.w);
  *(uint4*)dst = t.v;
}

// ---------------------------------------------------------------------------
// Coherent (agent-scope, cache-bypassing) loads for the CROSS-BLOCK MUTABLE
// buffers only (Abuf, Ghh). These emit sc1 loads that miss the local XCD L2,
// so consumers never see stale lines -- WITHOUT any buffer_inv that would
// nuke the read-only working set (Wg/Watt/u/fe/Gemb) cached across steps.
// ---------------------------------------------------------------------------
DEV uint2 cload8(const void* p) {
  unsigned long long v = __hip_atomic_load((const unsigned long long*)p,
      __ATOMIC_RELAXED, __HIP_MEMORY_SCOPE_AGENT);
  uint2 r; r.x = (u32)v; r.y = (u32)(v >> 32); return r;
}
DEV uint4 cload16(const void* p) {
  uint2 a = cload8(p);
  uint2 b = cload8((const char*)p + 8);
  return make_uint4(a.x, a.y, b.x, b.y);
}
DEV float cloadf(const float* p) {
  return __hip_atomic_load(p, __ATOMIC_RELAXED, __HIP_MEMORY_SCOPE_AGENT);
}

// ---------------------------------------------------------------------------
// Grid barrier WITHOUT whole-cache invalidation:
//  - __syncthreads drains every wave's stores (vmcnt(0)) before arrival;
//  - release fetch_add writes back dirty L2 lines (publishes plain stores);
//  - relaxed spin load (NO acquire -> no buffer_inv, L2 stays warm);
//  - consumers use cload* for mutable data, so no stale reads.
// Co-residency by capacity: 256 blocks = #CUs, 43KB LDS -> 3 blocks/CU cap.
// ---------------------------------------------------------------------------
DEV void gsync(int* bar, int target) {
  __syncthreads();
  __atomic_signal_fence(__ATOMIC_SEQ_CST);
  if (threadIdx.x == 0) {
    __hip_atomic_fetch_add(bar, 1, __ATOMIC_RELEASE, __HIP_MEMORY_SCOPE_AGENT);
    while (__hip_atomic_load(bar, __ATOMIC_RELAXED, __HIP_MEMORY_SCOPE_AGENT) < target)
      __builtin_amdgcn_s_sleep(2);
  }
  __atomic_signal_fence(__ATOMIC_SEQ_CST);
  __syncthreads();
}

__global__ void zero_bar_k(int* bar) { *bar = 0; }

// ---------------------------------------------------------------------------
// 128x128-tile bf16 MFMA GEMM, C = A[M,K] * B[N,K]^T + bias.  (unchanged)
// ---------------------------------------------------------------------------
__global__ __launch_bounds__(256) void gemm128_bt(
    const u16* __restrict__ A, int lda,
    const void* __restrict__ Bv, int ldb, int b_fp32,
    const float* __restrict__ bias,
    void* __restrict__ Cv, int ldc, int c_bf16,
    int N, int K, int swz)
{
  int m_tile, n_tile;
  if (swz) {
    int lin = blockIdx.y * gridDim.x + blockIdx.x;
    int idx = lin & 127;
    n_tile = (lin >> 7) * 8 + (idx & 7);
    m_tile = idx >> 3;
    if (n_tile >= ((N + 127) >> 7)) return;
  } else { m_tile = blockIdx.x; n_tile = blockIdx.y; }
  const int mBase = m_tile * 128;
  const int nBase = n_tile * 128;
  __shared__ u16 As[128 * 40];
  __shared__ u16 Bs[128 * 40];
  const int tid = threadIdx.x;
  const int lane = tid & 63;
  const int w = tid >> 6;
  const int wm = w >> 1, wn = w & 1;
  const int fr = (lane & 15);
  const int fq = (lane >> 4);

  f32x4 acc[4][4] = {};
  const int nk = K >> 5;
  for (int kt = 0; kt < nk; ++kt) {
    const int k0 = kt << 5;
    {
      int row0 = tid >> 2, k8 = (tid & 3) << 3;
      *(uint4*)&As[row0 * 40 + k8] =
          *(const uint4*)(A + (size_t)(mBase + row0) * lda + k0 + k8);
      int row1 = row0 + 64;
      *(uint4*)&As[row1 * 40 + k8] =
          *(const uint4*)(A + (size_t)(mBase + row1) * lda + k0 + k8);
    }
    {
      int row0 = tid >> 2, k8 = (tid & 3) << 3;
      for (int q = 0; q < 2; ++q) {
        int row = row0 + q * 64;
        int brow = nBase + row; if (brow > N - 1) brow = N - 1;
        if (b_fp32) {
          pack8((const float*)Bv + (size_t)brow * ldb + k0 + k8, &Bs[row * 40 + k8]);
        } else {
          *(uint4*)&Bs[row * 40 + k8] =
              *(const uint4*)((const u16*)Bv + (size_t)brow * ldb + k0 + k8);
        }
      }
    }
    __syncthreads();
    bf16x8 af[4], bfr[4];
#pragma unroll
    for (int i = 0; i < 4; ++i) {
      af[i]  = *(const bf16x8*)&As[(wm * 64 + i * 16 + fr) * 40 + fq * 8];
      bfr[i] = *(const bf16x8*)&Bs[(wn * 64 + i * 16 + fr) * 40 + fq * 8];
    }
#pragma unroll
    for (int mi = 0; mi < 4; ++mi)
#pragma unroll
      for (int ni = 0; ni < 4; ++ni)
        acc[mi][ni] = __builtin_amdgcn_mfma_f32_16x16x32_bf16(af[mi], bfr[ni], acc[mi][ni], 0, 0, 0);
    __syncthreads();
  }
#pragma unroll
  for (int mi = 0; mi < 4; ++mi) {
    int row = mBase + wm * 64 + mi * 16 + fq * 4;
#pragma unroll
    for (int ni = 0; ni < 4; ++ni) {
      int col = nBase + wn * 64 + ni * 16 + fr;
      if (col < N) {
        float bv = bias ? bias[col] : 0.0f;
#pragma unroll
        for (int r = 0; r < 4; ++r) {
          float v = acc[mi][ni][r] + bv;
          if (c_bf16) ((u16*)Cv)[(size_t)(row + r) * ldc + col] = f2bf(v);
          else        ((float*)Cv)[(size_t)(row + r) * ldc + col] = v;
        }
      }
    }
  }
}

// ---------------------------------------------------------------------------
// Setup-only M=64 GEMM (h0/c0).  (unchanged)
// ---------------------------------------------------------------------------
__global__ __launch_bounds__(256) void gemm64_bt(
    const u16* __restrict__ A, int lda,
    const float* __restrict__ B, int ldb,
    const float* __restrict__ bias,
    float* __restrict__ C, int ldc, int K)
{
  const int nBase = blockIdx.x * 64;
  __shared__ u16 As[64 * 40];
  __shared__ u16 Bs[64 * 40];
  const int tid = threadIdx.x;
  const int lane = tid & 63;
  const int w = tid >> 6;
  const int wm = w >> 1, wn = w & 1;
  const int fr = (lane & 15), fq = (lane >> 4);

  f32x4 acc[2][2] = {};
  const int nk = K >> 5;
  for (int kt = 0; kt < nk; ++kt) {
    const int k0 = kt << 5;
    int row = tid >> 2, k8 = (tid & 3) << 3;
    *(uint4*)&As[row * 40 + k8] = *(const uint4*)(A + (size_t)row * lda + k0 + k8);
    pack8(B + (size_t)(nBase + row) * ldb + k0 + k8, &Bs[row * 40 + k8]);
    __syncthreads();
    bf16x8 af[2], bfr[2];
#pragma unroll
    for (int i = 0; i < 2; ++i) {
      af[i]  = *(const bf16x8*)&As[(wm * 32 + i * 16 + fr) * 40 + fq * 8];
      bfr[i] = *(const bf16x8*)&Bs[(wn * 32 + i * 16 + fr) * 40 + fq * 8];
    }
#pragma unroll
    for (int mi = 0; mi < 2; ++mi)
#pragma unroll
      for (int ni = 0; ni < 2; ++ni)
        acc[mi][ni] = __builtin_amdgcn_mfma_f32_16x16x32_bf16(af[mi], bfr[ni], acc[mi][ni], 0, 0, 0);
    __syncthreads();
  }
#pragma unroll
  for (int mi = 0; mi < 2; ++mi) {
    int row = wm * 32 + mi * 16 + fq * 4;
#pragma unroll
    for (int ni = 0; ni < 2; ++ni) {
      int col = nBase + wn * 32 + ni * 16 + fr;
#pragma unroll
      for (int r = 0; r < 4; ++r)
        C[(size_t)(row + r) * ldc + col] = acc[mi][ni][r] + bias[col];
    }
  }
}

// ---------------------------------------------------------------------------
// Persistent kernel: the full 32-step recurrence in ONE launch.
// Grid = 256 blocks x 256 threads.  Per step:
//   Phase A: blocks 0-127  = attend (b=bid>>1, which=bid&1), incl. in-block
//            w_ah matvec; blocks 128-255 = Ghh = h @ Whh^T (K in [1280,1792)).
//   gsync
//   Phase B: blocks 0-127  = gates over K in [0,1280) ([ctx|pctx] @ Wih'),
//            epilogue adds Ghh + Gemb, runs LSTM cell -> h,c, Hall.
//   gsync
// Mutable cross-block data (Abuf, Ghh) is read via cload* (sc1, L2-bypass);
// all read-only data (Wg, Watt, u, fe, Gemb) keeps plain cached loads and
// stays L2-resident across all 32 steps (no buffer_inv anywhere).
// ---------------------------------------------------------------------------
__global__ __launch_bounds__(256) void step_loop(
    const u16* __restrict__ u_feat, const u16* __restrict__ u_art,
    const u16* __restrict__ feats_bf, const u16* __restrict__ arts_bf,
    const u16* __restrict__ Watt,
    const float* __restrict__ attWb, const float* __restrict__ paWb,
    const float* __restrict__ attAw, const float* __restrict__ attAb,
    const float* __restrict__ paAw, const float* __restrict__ paAb,
    const u16* __restrict__ Wg, const float* __restrict__ Gemb,
    float* __restrict__ Ghh,
    u16* __restrict__ Abuf, float* __restrict__ cbuf, u16* __restrict__ Hall,
    float* __restrict__ out_alpha, float* __restrict__ out_pa,
    int* __restrict__ bar)
{
  const int bid = blockIdx.x;
  const int tid = threadIdx.x;
  const int lane = tid & 63;
  const int w = tid >> 6;

  __shared__ float hs[512];          // h[b] as fp32 (attend path)
  __shared__ float wvs[512];         // w_ah slice (attend path)
  __shared__ float sc[196];
  __shared__ float red2[2];
  __shared__ float ctxred[4][768];
  __shared__ u16 As[16 * 136];       // gemm paths
  __shared__ u16 Bs[64 * 136];
  __shared__ float Gex[4][256];

  // attend-role constants
  const int which = bid & 1, b = bid >> 1;
  const int Nn = which ? 64 : 196;
  const int Dd = which ? 768 : 512;
  const u16* u  = which ? u_art + (size_t)b * 64 * 512 : u_feat + (size_t)b * 196 * 512;
  const u16* fe = which ? arts_bf + (size_t)b * 64 * 768 : feats_bf + (size_t)b * 196 * 512;
  const float* Aw = which ? paAw : attAw;
  const float Ab = which ? paAb[0] : attAb[0];
  const float* Wb = which ? paWb : attWb;
  const u16* Wrow0 = Watt + (size_t)(which * 512 + tid * 2) * 512;
  u16* ctxDst = Abuf + (size_t)b * 1792 + (which ? 512 : 0);

  // gemm-role constants
  const int gj = bid & 31, gmg = (bid >> 5) & 3;    // Phase B (bid<128)
  const int hidx = bid - 128;
  const int hj = hidx & 31, hmg = hidx >> 5;        // Phase A Ghh (bid>=128)
  const int g = w;                                  // wave = gate
  const int fr = lane & 15, fq = lane >> 4;

  float awr[8];
  if (bid < 128) {
#pragma unroll
    for (int j = 0; j < 8; ++j) awr[j] = Aw[lane * 8 + j];
  }

  int tgt = 0;
  for (int t = 0; t < 32; ++t) {
    // ================= Phase A =================
    if (bid < 128) {
      // ---- h -> LDS (fp32); h is cross-block mutable -> coherent load ----
      if (tid < 64) {
        union { uint4 v; u16 us[8]; } hv;
        hv.v = cload16(Abuf + (size_t)b * 1792 + 1280 + tid * 8);
#pragma unroll
        for (int j = 0; j < 8; ++j) hs[tid * 8 + j] = bf2f(hv.us[j]);
      }
      __syncthreads();
      // ---- wv = h @ Watt_half^T + Wb  (thread owns cols 2*tid, 2*tid+1) ----
      {
        float a0 = 0.0f, a1 = 0.0f;
        for (int k = 0; k < 512; k += 8) {
          union { uint4 v; u16 us[8]; } r0, r1;
          r0.v = *(const uint4*)(Wrow0 + k);
          r1.v = *(const uint4*)(Wrow0 + 512 + k);
#pragma unroll
          for (int j = 0; j < 8; ++j) {
            float hv = hs[k + j];
            a0 += bf2f(r0.us[j]) * hv;
            a1 += bf2f(r1.us[j]) * hv;
          }
        }
        wvs[tid * 2]     = a0 + Wb[tid * 2];
        wvs[tid * 2 + 1] = a1 + Wb[tid * 2 + 1];
      }
      __syncthreads();
      float wvr[8];
#pragma unroll
      for (int j = 0; j < 8; ++j) wvr[j] = wvs[lane * 8 + j];
      // ---- scores ----
      for (int n = w; n < Nn; n += 4) {
        union { uint4 v; u16 us[8]; } uv;
        uv.v = *(const uint4*)(u + (size_t)n * 512 + lane * 8);
        float p = 0.0f;
#pragma unroll
        for (int j = 0; j < 8; ++j)
          p += tanh_(bf2f(uv.us[j]) + wvr[j]) * awr[j];
#pragma unroll
        for (int off = 32; off > 0; off >>= 1) p += __shfl_down(p, off);
        if (lane == 0) sc[n] = p + Ab;
      }
      __syncthreads();
      // ---- softmax stats ----
      if (w == 0) {
        float m = -1e30f;
        for (int n = lane; n < Nn; n += 64) m = fmaxf(m, sc[n]);
#pragma unroll
        for (int off = 32; off > 0; off >>= 1) m = fmaxf(m, __shfl_xor(m, off));
        float s = 0.0f;
        for (int n = lane; n < Nn; n += 64) s += __expf(sc[n] - m);
#pragma unroll
        for (int off = 32; off > 0; off >>= 1) s += __shfl_xor(s, off);
        if (lane == 0) { red2[0] = m; red2[1] = s; }
      }
      __syncthreads();
      const float m = red2[0], inv = frcp(red2[1]);
      float* aout = which ? out_pa + (size_t)(b * 32 + t) * 64
                          : out_alpha + (size_t)(b * 32 + t) * 196;
      for (int n = tid; n < Nn; n += 256) {
        float a = __expf(sc[n] - m) * inv;
        sc[n] = a;
        aout[n] = a;
      }
      __syncthreads();
      // ---- ctx ----
      float a0[8] = {0,0,0,0,0,0,0,0}, a1[8] = {0,0,0,0,0,0,0,0};
      const bool two = (Dd == 768) && (lane < 32);
      for (int n = w; n < Nn; n += 4) {
        const float a = sc[n];
        union { uint4 v; u16 us[8]; } v0;
        v0.v = *(const uint4*)(fe + (size_t)n * Dd + lane * 8);
#pragma unroll
        for (int j = 0; j < 8; ++j) a0[j] += a * bf2f(v0.us[j]);
        if (two) {
          union { uint4 v; u16 us[8]; } v1;
          v1.v = *(const uint4*)(fe + (size_t)n * Dd + 512 + lane * 8);
#pragma unroll
          for (int j = 0; j < 8; ++j) a1[j] += a * bf2f(v1.us[j]);
        }
      }
      {
        float4* dst = (float4*)&ctxred[w][lane * 8];
        dst[0] = make_float4(a0[0], a0[1], a0[2], a0[3]);
        dst[1] = make_float4(a0[4], a0[5], a0[6], a0[7]);
        if (two) {
          float4* d2 = (float4*)&ctxred[w][512 + lane * 8];
          d2[0] = make_float4(a1[0], a1[1], a1[2], a1[3]);
          d2[1] = make_float4(a1[4], a1[5], a1[6], a1[7]);
        }
      }
      __syncthreads();
      for (int d = tid; d < Dd; d += 256)
        ctxDst[d] = f2bf(ctxred[0][d] + ctxred[1][d] + ctxred[2][d] + ctxred[3][d]);
    } else {
      // ---- Ghh tile: h @ Whh^T  (Wg cols [1280,1792)); h -> coherent ----
      f32x4 acc = {};
      for (int kt = 10; kt < 14; ++kt) {
        const int k0 = kt * 128;
        {
          int r = tid >> 4, kc = (tid & 15) << 3;
          *(uint4*)&As[r * 136 + kc] =
              cload16(Abuf + (size_t)(hmg * 16 + r) * 1792 + k0 + kc);
        }
#pragma unroll
        for (int q = 0; q < 4; ++q) {
          int idx = tid + q * 256;
          int r6 = idx >> 4, kc = (idx & 15) << 3;
          int gg = r6 >> 4, rr = r6 & 15;
          *(uint4*)&Bs[r6 * 136 + kc] =
              *(const uint4*)(Wg + (size_t)(gg * 512 + hj * 16 + rr) * 1792 + k0 + kc);
        }
        __syncthreads();
#pragma unroll
        for (int ks = 0; ks < 4; ++ks) {
          bf16x8 af = *(const bf16x8*)&As[fr * 136 + ks * 32 + fq * 8];
          bf16x8 bf = *(const bf16x8*)&Bs[(g * 16 + fr) * 136 + ks * 32 + fq * 8];
          acc = __builtin_amdgcn_mfma_f32_16x16x32_bf16(af, bf, acc, 0, 0, 0);
        }
        __syncthreads();
      }
#pragma unroll
      for (int r = 0; r < 4; ++r)
        Ghh[(size_t)(hmg * 16 + fq * 4 + r) * 2048 + g * 512 + hj * 16 + fr] = acc[r];
    }
    tgt += 256; gsync(bar, tgt);
    // ================= Phase B =================
    if (bid < 128) {
      f32x4 acc = {};
      for (int kt = 0; kt < 10; ++kt) {
        const int k0 = kt * 128;
        {
          int r = tid >> 4, kc = (tid & 15) << 3;
          *(uint4*)&As[r * 136 + kc] =
              cload16(Abuf + (size_t)(gmg * 16 + r) * 1792 + k0 + kc);
        }
#pragma unroll
        for (int q = 0; q < 4; ++q) {
          int idx = tid + q * 256;
          int r6 = idx >> 4, kc = (idx & 15) << 3;
          int gg = r6 >> 4, rr = r6 & 15;
          *(uint4*)&Bs[r6 * 136 + kc] =
              *(const uint4*)(Wg + (size_t)(gg * 512 + gj * 16 + rr) * 1792 + k0 + kc);
        }
        __syncthreads();
#pragma unroll
        for (int ks = 0; ks < 4; ++ks) {
          bf16x8 af = *(const bf16x8*)&As[fr * 136 + ks * 32 + fq * 8];
          bf16x8 bf = *(const bf16x8*)&Bs[(g * 16 + fr) * 136 + ks * 32 + fq * 8];
          acc = __builtin_amdgcn_mfma_f32_16x16x32_bf16(af, bf, acc, 0, 0, 0);
        }
        __syncthreads();
      }
#pragma unroll
      for (int r = 0; r < 4; ++r)
        Gex[g][(fq * 4 + r) * 16 + fr] = acc[r];
      __syncthreads();
      {
        const int bl = tid >> 4, dl = tid & 15;
        const int bb = gmg * 16 + bl;
        const int d = gj * 16 + dl;
        const float* ge = Gemb + (size_t)(bb * 32 + t) * 2048;
        const float* gh = Ghh + (size_t)bb * 2048;
        float iv = Gex[0][tid] + ge[d]        + cloadf(gh + d);
        float fv = Gex[1][tid] + ge[512 + d]  + cloadf(gh + 512 + d);
        float gv = Gex[2][tid] + ge[1024 + d] + cloadf(gh + 1024 + d);
        float ov = Gex[3][tid] + ge[1536 + d] + cloadf(gh + 1536 + d);
        float c_old = cbuf[bb * 512 + d];
        float cn = sigm(fv) * c_old + sigm(iv) * tanh_(gv);
        float hn = sigm(ov) * tanh_(cn);
        cbuf[bb * 512 + d] = cn;
        u16 hb = f2bf(hn);
        Abuf[(size_t)bb * 1792 + 1280 + d] = hb;
        Hall[(size_t)(bb * 32 + t) * 512 + d] = hb;
      }
    }
    tgt += 256; gsync(bar, tgt);
  }
}

// --------------------------- small setup kernels ---------------------------

__global__ void convert_bf16_k(const float* __restrict__ src, u16* __restrict__ dst) {
  size_t i4 = ((size_t)blockIdx.x * 256 + threadIdx.x) * 4;
  float4 v = *(const float4*)(src + i4);
  union { u16 us[4]; uint2 u; } t;
  t.us[0] = f2bf(v.x); t.us[1] = f2bf(v.y); t.us[2] = f2bf(v.z); t.us[3] = f2bf(v.w);
  *(uint2*)(dst + i4) = t.u;
}

// W_gates[2048,1792] bf16 = [Wih cols 512:1792 | Whh cols 0:512]
__global__ void wgates_k(const float* __restrict__ Wih, const float* __restrict__ Whh,
                         u16* __restrict__ dst) {
  int c = blockIdx.x * 256 + threadIdx.x;     // 458752 chunk-8s
  int r = c / 224;
  int k8 = (c - r * 224) * 8;
  const float* src = (k8 < 1280) ? (Wih + (size_t)r * 1792 + 512 + k8)
                                 : (Whh + (size_t)r * 512 + (k8 - 1280));
  pack8(src, dst + (size_t)r * 1792 + k8);
}

__global__ void biassum_k(const float* __restrict__ a, const float* __restrict__ b,
                          float* __restrict__ dst) {
  int i = blockIdx.x * 256 + threadIdx.x;
  dst[i] = a[i] + b[i];
}

__global__ void gather_emb_k(const int* __restrict__ captions, const float* __restrict__ emb,
                             u16* __restrict__ Emb_all) {
  int c = blockIdx.x * 256 + threadIdx.x;
  int r = c >> 7;
  int c4 = (c & 127) << 2;
  int v = captions[r];
  float4 x = *(const float4*)(emb + (size_t)v * 512 + c4);
  union { u16 us[4]; uint2 u; } t;
  t.us[0] = f2bf(x.x); t.us[1] = f2bf(x.y); t.us[2] = f2bf(x.z); t.us[3] = f2bf(x.w);
  *(uint2*)(Emb_all + (size_t)r * 512 + c4) = t.u;
}

__global__ void meanpool_k(const float* __restrict__ features, const float* __restrict__ articles,
                           u16* __restrict__ inp0_bf) {
  int b = blockIdx.x, tid = threadIdx.x;
  for (int d = tid; d < 1280; d += 256) {
    float s = 0.0f;
    if (d < 512) {
      for (int n = 0; n < 196; ++n) s += features[((size_t)b * 196 + n) * 512 + d];
      s *= (1.0f / 196.0f);
    } else {
      int dd = d - 512;
      for (int n = 0; n < 64; ++n) s += articles[((size_t)b * 64 + n) * 768 + dd];
      s *= (1.0f / 64.0f);
    }
    inp0_bf[b * 1280 + d] = f2bf(s);
  }
}

__global__ void h0prep_k(const float* __restrict__ hbuf, u16* __restrict__ Abuf) {
  int i = blockIdx.x * 256 + threadIdx.x;     // 32768
  Abuf[(size_t)(i >> 9) * 1792 + 1280 + (i & 511)] = f2bf(hbuf[i]);
}

// ---------------------------------------------------------------------------

extern "C" void kernel_launch(void* const* d_in, const int* in_sizes, int n_in,
                              void* d_out, int out_size, void* d_ws, size_t ws_size,
                              hipStream_t stream) {
  const float* features = (const float*)d_in[0];
  const float* articles = (const float*)d_in[1];
  const int*   captions = (const int*)d_in[2];
  const float* emb      = (const float*)d_in[3];
  const float* att_W_w  = (const float*)d_in[4];
  const float* att_W_b  = (const float*)d_in[5];
  const float* att_U_w  = (const float*)d_in[6];
  const float* att_U_b  = (const float*)d_in[7];
  const float* att_A_w  = (const float*)d_in[8];
  const float* att_A_b  = (const float*)d_in[9];
  const float* pa_W_w   = (const float*)d_in[10];
  const float* pa_W_b   = (const float*)d_in[11];
  const float* pa_U_w   = (const float*)d_in[12];
  const float* pa_U_b   = (const float*)d_in[13];
  const float* pa_A_w   = (const float*)d_in[14];
  const float* pa_A_b   = (const float*)d_in[15];
  const float* init_h_w = (const float*)d_in[16];
  const float* init_h_b = (const float*)d_in[17];
  const float* init_c_w = (const float*)d_in[18];
  const float* init_c_b = (const float*)d_in[19];
  const float* lstm_w_ih = (const float*)d_in[20];
  const float* lstm_w_hh = (const float*)d_in[21];
  const float* lstm_b_ih = (const float*)d_in[22];
  const float* lstm_b_hh = (const float*)d_in[23];
  const float* fcn_w    = (const float*)d_in[24];
  const float* fcn_b    = (const float*)d_in[25];

  float* out = (float*)d_out;
  float* out_preds = out;                       // [64,32,30000]
  float* out_alpha = out + 61440000ull;         // [64,32,196]
  float* out_pa    = out + 61841408ull;         // [64,32,64]

  uintptr_t p = (uintptr_t)d_ws;
  auto take = [&](size_t bytes) -> uintptr_t {
    uintptr_t r = p; p += (bytes + 255) & ~(size_t)255; return r;
  };
  u16* features_bf = (u16*)take(6422528ull * 2);   // [64*196,512]; fcn_bf alias after loop
  u16* articles_bf = (u16*)take(3145728ull * 2);   // [64*64,768]
  u16* u_feat      = (u16*)take(6422528ull * 2);   // [64*196,512]
  u16* u_art       = (u16*)take(2097152ull * 2);   // [64*64,512]
  u16* Emb_all     = (u16*)take(2048ull * 512 * 2);
  u16* inp0_bf     = (u16*)take(64ull * 1280 * 2);
  float* hbuf      = (float*)take(64ull * 512 * 4);
  float* cbuf      = (float*)take(64ull * 512 * 4);
  u16* Abuf        = (u16*)take(64ull * 1792 * 2); // [ctx|pctx|h] per b
  float* Ghh       = (float*)take(64ull * 2048 * 4); // h @ Whh^T per step
  u16* Hall        = (u16*)take(2048ull * 512 * 2);
  u16* Watt        = (u16*)take(1024ull * 512 * 2);
  u16* Wg          = (u16*)take(2048ull * 1792 * 2);
  float* Gemb      = (float*)take(2048ull * 2048 * 4);
  float* bsum      = (float*)take(2048ull * 4);
  int* bar         = (int*)take(256);
  u16* fcn_bf      = features_bf;                  // aliased (dead after loop)
  (void)ws_size; (void)in_sizes; (void)n_in; (void)out_size;

  // ---- one-time setup ----
  convert_bf16_k<<<6272, 256, 0, stream>>>(features, features_bf);
  convert_bf16_k<<<3072, 256, 0, stream>>>(articles, articles_bf);
  convert_bf16_k<<<256, 256, 0, stream>>>(att_W_w, Watt);
  convert_bf16_k<<<256, 256, 0, stream>>>(pa_W_w, Watt + 262144);
  wgates_k<<<1792, 256, 0, stream>>>(lstm_w_ih, lstm_w_hh, Wg);
  biassum_k<<<8, 256, 0, stream>>>(lstm_b_ih, lstm_b_hh, bsum);
  gather_emb_k<<<1024, 256, 0, stream>>>(captions, emb, Emb_all);
  meanpool_k<<<64, 256, 0, stream>>>(features, articles, inp0_bf);
  gemm128_bt<<<dim3(98, 4), 256, 0, stream>>>(features_bf, 512, att_U_w, 512, 1,
                                              att_U_b, u_feat, 512, 1, 512, 512, 0);
  gemm128_bt<<<dim3(32, 4), 256, 0, stream>>>(articles_bf, 768, pa_U_w, 768, 1,
                                              pa_U_b, u_art, 512, 1, 512, 768, 0);
  // Gemb[2048,2048] = Emb_all @ Wih[:, :512]^T + (bih + bhh)
  gemm128_bt<<<dim3(16, 16), 256, 0, stream>>>(Emb_all, 512, lstm_w_ih, 1792, 1,
                                               bsum, Gemb, 2048, 0, 2048, 512, 0);
  gemm64_bt<<<8, 256, 0, stream>>>(inp0_bf, 1280, init_h_w, 1280, init_h_b, hbuf, 512, 1280);
  gemm64_bt<<<8, 256, 0, stream>>>(inp0_bf, 1280, init_c_w, 1280, init_c_b, cbuf, 512, 1280);
  h0prep_k<<<128, 256, 0, stream>>>(hbuf, Abuf);

  // ---- recurrence: single persistent kernel (plain launch; co-residency by
  // capacity: 256 blocks = #CUs, LDS 43KB -> 3 blocks/CU capacity) ----
  zero_bar_k<<<1, 1, 0, stream>>>(bar);
  step_loop<<<dim3(256), dim3(256), 0, stream>>>(
      u_feat, u_art, features_bf, articles_bf, Watt,
      att_W_b, pa_W_b, att_A_w, att_A_b, pa_A_w, pa_A_b,
      Wg, Gemb, Ghh, Abuf, cbuf, Hall, out_alpha, out_pa, bar);

  // ---- preds = Hall @ fcn_w^T + fcn_b (fcn_bf aliases dead staging region) ----
  convert_bf16_k<<<15000, 256, 0, stream>>>(fcn_w, fcn_bf);
  gemm128_bt<<<dim3(16, 240), 256, 0, stream>>>(Hall, 512, fcn_bf, 512, 0,
                                                fcn_b, out_preds, 30000, 0,
                                                30000, 512, 1);
}